// Round 11
// baseline (317.515 us; speedup 1.0000x reference)
//
#include <hip/hip_runtime.h>
#include <hip/hip_bf16.h>
#include <cstdint>

// ---------------------------------------------------------------------------
// TextBlock: BN -> {q,k,v} -> MHSA (NH=16, KD=16, D=64, N=1024) -> proj -> +res
//            -> BN -> MLP(1024, relu6) -> +res.   B=8, C=256.
// I/O FLOAT32. Intermediates bf16 for MFMA, fp32 accumulation.
// R11: attn = 2048 blocks x 64 rows (R8 geometry, NO reg pipeline, bound 4 -
//      both spill causes removed). GEMMs back to proven 64x64/(256,4).
//      bn_apply_t#2 deleted: proj writes xf1_t (n-major bf16) + fused BN2
//      stats; MLP1 applies BN2 inline at staging; MLP2 gathers res from xf1_t.
// ---------------------------------------------------------------------------

typedef __attribute__((ext_vector_type(8))) short short8;
typedef __attribute__((ext_vector_type(4))) float floatx4;

#define QK_SC 5.770780163555851f   // sqrt(kd)=4 times log2(e), folded into Q

__device__ __forceinline__ float b2f(unsigned short u) {
  union { unsigned int i; float f; } x; x.i = ((unsigned int)u) << 16; return x.f;
}
__device__ __forceinline__ unsigned short f2b(float f) {
  union { float f; unsigned int i; } x; x.f = f;
  unsigned int r = x.i + 0x7FFFu + ((x.i >> 16) & 1u);   // RNE
  return (unsigned short)(r >> 16);
}
// packed f32x2 -> bf16x2 (v_cvt_pk_bf16_f32 on gfx950)
__device__ __forceinline__ unsigned int f2b2(float a, float b) {
  __hip_bfloat162 h = __float22bfloat162_rn(make_float2(a, b));
  union { __hip_bfloat162 v; unsigned int u; } x; x.v = h; return x.u;
}

// ---------------------------------------------------------------------------
// prep: blocks 0..1151 convert the 6 weight mats f32->bf16 into wb;
//       blocks 1152..3199 accumulate BN1 partial sums of x into bnacc;
//       blocks 3200..3205 concat bq|bk|bv into biasqkv.
// ---------------------------------------------------------------------------
__global__ __launch_bounds__(256) void prep(
    const float* __restrict__ s0, const float* __restrict__ s1,
    const float* __restrict__ s2, const float* __restrict__ s3,
    const float* __restrict__ s4, const float* __restrict__ s5,
    unsigned short* __restrict__ dst,
    const float* __restrict__ x, float* __restrict__ acc,
    const float* __restrict__ bq, const float* __restrict__ bk,
    const float* __restrict__ bv, float* __restrict__ biasqkv) {
  int blk = blockIdx.x, t = threadIdx.x;
  if (blk < 1152) {
    int i = blk * 256 + t;   // float4-group index
    if (i >= 294912) return;
    const float* s; int li; size_t dbase;
    if (i < 16384)       { s = s0; li = i;          dbase = 0; }
    else if (i < 32768)  { s = s1; li = i - 16384;  dbase = 65536; }
    else if (i < 98304)  { s = s2; li = i - 32768;  dbase = 131072; }
    else if (i < 163840) { s = s3; li = i - 98304;  dbase = 393216; }
    else if (i < 229376) { s = s4; li = i - 163840; dbase = 655360; }
    else                 { s = s5; li = i - 229376; dbase = 917504; }
    float4 v = ((const float4*)s)[li];
    uint2 o; o.x = f2b2(v.x, v.y); o.y = f2b2(v.z, v.w);
    ((uint2*)(dst + dbase))[li] = o;
  } else if (blk < 3200) {
    int blk2 = blk - 1152;
    int b = blk2 >> 8, c = blk2 & 255;
    const float* p = x + (((size_t)(b * 256 + c)) << 10);
    float4 v = ((const float4*)p)[t];
    float s = (v.x + v.y) + (v.z + v.w);
    float s2 = (v.x * v.x + v.y * v.y) + (v.z * v.z + v.w * v.w);
    #pragma unroll
    for (int o = 32; o > 0; o >>= 1) { s += __shfl_down(s, o, 64); s2 += __shfl_down(s2, o, 64); }
    __shared__ float rs[4], rs2[4];
    int w = t >> 6;
    if ((t & 63) == 0) { rs[w] = s; rs2[w] = s2; }
    __syncthreads();
    if (t == 0) {
      atomicAdd(acc + c, (rs[0] + rs[1]) + (rs[2] + rs[3]));
      atomicAdd(acc + 256 + c, (rs2[0] + rs2[1]) + (rs2[2] + rs2[3]));
    }
  } else {
    int i = (blk - 3200) * 256 + t;   // 0..1535
    float v = (i < 256) ? bq[i] : (i < 512) ? bk[i - 256] : bv[i - 512];
    biasqkv[i] = v;
  }
}

// ---------------------------------------------------------------------------
// BN apply + transpose (finalize fused): x[b][c][n] f32 -> y_t[b][n][c] bf16.
// ---------------------------------------------------------------------------
__global__ __launch_bounds__(256) void bn_apply_t(
    const float* __restrict__ x, const float* __restrict__ acc,
    const float* __restrict__ g, const float* __restrict__ bb,
    unsigned short* __restrict__ yt) {
  int nt = blockIdx.x, ct = blockIdx.y, b = blockIdx.z;
  int t = threadIdx.x;
  __shared__ unsigned short T[64][72];
  {
    int r = t >> 2, g4 = (t & 3) * 16;
    int c = ct * 64 + r;
    float m = acc[c] * (1.0f / 8192.0f);
    float var = acc[256 + c] * (1.0f / 8192.0f) - m * m;
    float scl = g[c] * rsqrtf(var + 1e-5f);
    float shf = bb[c] - m * scl;
    const float* p = x + (((size_t)(b * 256 + c)) << 10) + nt * 64 + g4;
    float4 u0 = *(const float4*)(p);
    float4 u1 = *(const float4*)(p + 4);
    float4 u2 = *(const float4*)(p + 8);
    float4 u3 = *(const float4*)(p + 12);
    uint4 o0, o1;
    o0.x = f2b2(fmaf(u0.x, scl, shf), fmaf(u0.y, scl, shf));
    o0.y = f2b2(fmaf(u0.z, scl, shf), fmaf(u0.w, scl, shf));
    o0.z = f2b2(fmaf(u1.x, scl, shf), fmaf(u1.y, scl, shf));
    o0.w = f2b2(fmaf(u1.z, scl, shf), fmaf(u1.w, scl, shf));
    o1.x = f2b2(fmaf(u2.x, scl, shf), fmaf(u2.y, scl, shf));
    o1.y = f2b2(fmaf(u2.z, scl, shf), fmaf(u2.w, scl, shf));
    o1.z = f2b2(fmaf(u3.x, scl, shf), fmaf(u3.y, scl, shf));
    o1.w = f2b2(fmaf(u3.z, scl, shf), fmaf(u3.w, scl, shf));
    *(uint4*)&T[r][g4] = o0;
    *(uint4*)&T[r][g4 + 8] = o1;
  }
  __syncthreads();
  {
    int nr = t >> 2, cg = (t & 3) * 16;
    unsigned int ob[8];
    #pragma unroll
    for (int j = 0; j < 8; ++j) {
      unsigned int lo = T[cg + 2 * j][nr];
      unsigned int hi = T[cg + 2 * j + 1][nr];
      ob[j] = lo | (hi << 16);
    }
    unsigned short* orow = yt + ((size_t)(b * 1024 + nt * 64 + nr)) * 256 + ct * 64 + cg;
    *(uint4*)&orow[0] = make_uint4(ob[0], ob[1], ob[2], ob[3]);
    *(uint4*)&orow[8] = make_uint4(ob[4], ob[5], ob[6], ob[7]);
  }
}

// ---------------------------------------------------------------------------
// MFMA GEMM (64x64, BK=64, (256,4) - proven R7 shape):
//   out = W[M,K] @ Bn_b[N=1024,K]^T + bias (...)
// MODE 4: fused QKV (M=1536): rows<256 q*SC | <512 k (per-head [b][h][n][16])
//         | else v k-major bf16. kt at out+2097152, vt at out+4194304.
// MODE 5: proj: out xf1_t N-MAJOR bf16 [b][1024][256] + x residual (f32
//         c-major) + fused BN2 stats atomics into stats[].
// MODE 6: MLP1: B-staging applies BN2 inline (scl/shf from bnin/g/bb, LDS
//         precomputed) + relu6 -> N-MAJOR bf16 out [b][1024][1024] (hb_t).
// MODE 7: MLP2: res gathered from resb (bf16 n-major xf1_t) -> f32 out
//         c-major [b][256][1024] (d_out).
// ---------------------------------------------------------------------------
template <int MODE>
__global__ __launch_bounds__(256, 4) void gemm3(
    const unsigned short* __restrict__ W, const unsigned short* __restrict__ Bn,
    const float* __restrict__ bias, const float* __restrict__ resf,
    const unsigned short* __restrict__ resb, void* __restrict__ outv,
    float* __restrict__ stats, const float* __restrict__ bnin,
    const float* __restrict__ g, const float* __restrict__ bb, int M, int K) {
  int n0 = blockIdx.x * 64, m0 = blockIdx.y * 64, b = blockIdx.z;
  int t = threadIdx.x, lane = t & 63, w = t >> 6;
  int ml = lane & 15, quad = lane >> 4;

  __shared__ unsigned short Wt[64][72];
  __shared__ unsigned short Yt[64][72];
  __shared__ float Scl[256], Shf[256];

  if (MODE == 6) {   // precompute BN2 scale/shift (c = t)
    float m = bnin[t] * (1.0f / 8192.0f);
    float var = bnin[256 + t] * (1.0f / 8192.0f) - m * m;
    float scl = g[t] * rsqrtf(var + 1e-5f);
    Scl[t] = scl;
    Shf[t] = bb[t] - m * scl;
    __syncthreads();
  }

  const unsigned short* Bp = Bn + (size_t)b * 1024 * K;
  int sr = t >> 2, scg = (t & 3) * 16;
  const unsigned short* wrow = W + (size_t)(m0 + sr) * K + scg;
  const unsigned short* brow = Bp + (size_t)(n0 + sr) * K + scg;

  floatx4 acc[4];
  #pragma unroll
  for (int i = 0; i < 4; ++i) acc[i] = (floatx4){0.f, 0.f, 0.f, 0.f};

  for (int k0 = 0; k0 < K; k0 += 64) {
    *(uint4*)&Wt[sr][scg]     = *(const uint4*)(wrow + k0);
    *(uint4*)&Wt[sr][scg + 8] = *(const uint4*)(wrow + k0 + 8);
    if (MODE == 6) {   // BN2-apply inline: y2 = xf1*scl + shf
      uint4 r0 = *(const uint4*)(brow + k0);
      uint4 r1 = *(const uint4*)(brow + k0 + 8);
      int cb = k0 + scg;
      float4 s0 = *(const float4*)&Scl[cb],     h0 = *(const float4*)&Shf[cb];
      float4 s1 = *(const float4*)&Scl[cb + 4], h1 = *(const float4*)&Shf[cb + 4];
      float4 s2 = *(const float4*)&Scl[cb + 8], h2 = *(const float4*)&Shf[cb + 8];
      float4 s3 = *(const float4*)&Scl[cb + 12], h3 = *(const float4*)&Shf[cb + 12];
      uint4 o0, o1;
      o0.x = f2b2(fmaf(b2f(r0.x & 0xffff), s0.x, h0.x), fmaf(b2f(r0.x >> 16), s0.y, h0.y));
      o0.y = f2b2(fmaf(b2f(r0.y & 0xffff), s0.z, h0.z), fmaf(b2f(r0.y >> 16), s0.w, h0.w));
      o0.z = f2b2(fmaf(b2f(r0.z & 0xffff), s1.x, h1.x), fmaf(b2f(r0.z >> 16), s1.y, h1.y));
      o0.w = f2b2(fmaf(b2f(r0.w & 0xffff), s1.z, h1.z), fmaf(b2f(r0.w >> 16), s1.w, h1.w));
      o1.x = f2b2(fmaf(b2f(r1.x & 0xffff), s2.x, h2.x), fmaf(b2f(r1.x >> 16), s2.y, h2.y));
      o1.y = f2b2(fmaf(b2f(r1.y & 0xffff), s2.z, h2.z), fmaf(b2f(r1.y >> 16), s2.w, h2.w));
      o1.z = f2b2(fmaf(b2f(r1.z & 0xffff), s3.x, h3.x), fmaf(b2f(r1.z >> 16), s3.y, h3.y));
      o1.w = f2b2(fmaf(b2f(r1.w & 0xffff), s3.z, h3.z), fmaf(b2f(r1.w >> 16), s3.w, h3.w));
      *(uint4*)&Yt[sr][scg]     = o0;
      *(uint4*)&Yt[sr][scg + 8] = o1;
    } else {
      *(uint4*)&Yt[sr][scg]     = *(const uint4*)(brow + k0);
      *(uint4*)&Yt[sr][scg + 8] = *(const uint4*)(brow + k0 + 8);
    }
    __syncthreads();
    short8 a0 = *(const short8*)&Wt[w * 16 + ml][quad * 8];
    short8 a1 = *(const short8*)&Wt[w * 16 + ml][32 + quad * 8];
    #pragma unroll
    for (int nt2 = 0; nt2 < 4; ++nt2) {
      short8 b0 = *(const short8*)&Yt[nt2 * 16 + ml][quad * 8];
      short8 b1 = *(const short8*)&Yt[nt2 * 16 + ml][32 + quad * 8];
      acc[nt2] = __builtin_amdgcn_mfma_f32_16x16x32_bf16(a0, b0, acc[nt2], 0, 0, 0);
      acc[nt2] = __builtin_amdgcn_mfma_f32_16x16x32_bf16(a1, b1, acc[nt2], 0, 0, 0);
    }
    __syncthreads();
  }

  int row_base = m0 + w * 16 + quad * 4;

  if (MODE == 4) {
    int hh = row_base >> 4;       // 0..95
    float b0 = bias[row_base + 0], b1 = bias[row_base + 1];
    float b2 = bias[row_base + 2], b3 = bias[row_base + 3];
    if (hh < 32) {                // q (hh<16) or k
      unsigned short* qkout = (unsigned short*)outv + ((hh < 16) ? 0 : 2097152);
      float os = (hh < 16) ? QK_SC : 1.0f;
      int head = hh & 15, kd0 = row_base & 15;
      #pragma unroll
      for (int c = 0; c < 4; ++c) {
        int col = n0 + c * 16 + ml;
        uint2 pw;
        pw.x = f2b2((acc[c][0] + b0) * os, (acc[c][1] + b1) * os);
        pw.y = f2b2((acc[c][2] + b2) * os, (acc[c][3] + b3) * os);
        *(uint2*)&qkout[(((size_t)b * 16 + head) * 1024 + col) * 16 + kd0] = pw;
      }
    } else {                      // v: k-major [b][d][1024]
      unsigned short* vout = (unsigned short*)outv + 4194304;
      int d0 = row_base - 512;
      #pragma unroll
      for (int c = 0; c < 4; ++c) {
        int col = n0 + c * 16 + ml;
        vout[((size_t)b * 1024 + d0 + 0) * 1024 + col] = f2b(acc[c][0] + b0);
        vout[((size_t)b * 1024 + d0 + 1) * 1024 + col] = f2b(acc[c][1] + b1);
        vout[((size_t)b * 1024 + d0 + 2) * 1024 + col] = f2b(acc[c][2] + b2);
        vout[((size_t)b * 1024 + d0 + 3) * 1024 + col] = f2b(acc[c][3] + b3);
      }
    }
  } else if (MODE == 5) {          // proj -> xf1_t n-major bf16 + stats
    unsigned short* outp = (unsigned short*)outv;
    float vsum[4] = {0.f, 0.f, 0.f, 0.f}, vsq[4] = {0.f, 0.f, 0.f, 0.f};
    #pragma unroll
    for (int c = 0; c < 4; ++c) {
      int col = n0 + c * 16 + ml;
      float v0 = acc[c][0] + bias[row_base + 0] + resf[((size_t)b * 256 + row_base + 0) * 1024 + col];
      float v1 = acc[c][1] + bias[row_base + 1] + resf[((size_t)b * 256 + row_base + 1) * 1024 + col];
      float v2 = acc[c][2] + bias[row_base + 2] + resf[((size_t)b * 256 + row_base + 2) * 1024 + col];
      float v3 = acc[c][3] + bias[row_base + 3] + resf[((size_t)b * 256 + row_base + 3) * 1024 + col];
      vsum[0] += v0; vsq[0] += v0 * v0;
      vsum[1] += v1; vsq[1] += v1 * v1;
      vsum[2] += v2; vsq[2] += v2 * v2;
      vsum[3] += v3; vsq[3] += v3 * v3;
      uint2 pw; pw.x = f2b2(v0, v1); pw.y = f2b2(v2, v3);
      *(uint2*)&outp[((size_t)b * 1024 + col) * 256 + row_base] = pw;
    }
    #pragma unroll
    for (int r = 0; r < 4; ++r) {
      float s = vsum[r], q = vsq[r];
      #pragma unroll
      for (int o = 1; o < 16; o <<= 1) { s += __shfl_xor(s, o, 64); q += __shfl_xor(q, o, 64); }
      if (ml == 0) {
        atomicAdd(stats + row_base + r, s);
        atomicAdd(stats + 256 + row_base + r, q);
      }
    }
  } else if (MODE == 6) {          // MLP1 -> hb_t n-major bf16 + relu6
    unsigned short* outp = (unsigned short*)outv;
    #pragma unroll
    for (int c = 0; c < 4; ++c) {
      int col = n0 + c * 16 + ml;
      float v0 = fminf(fmaxf(acc[c][0] + bias[row_base + 0], 0.f), 6.f);
      float v1 = fminf(fmaxf(acc[c][1] + bias[row_base + 1], 0.f), 6.f);
      float v2 = fminf(fmaxf(acc[c][2] + bias[row_base + 2], 0.f), 6.f);
      float v3 = fminf(fmaxf(acc[c][3] + bias[row_base + 3], 0.f), 6.f);
      uint2 pw; pw.x = f2b2(v0, v1); pw.y = f2b2(v2, v3);
      *(uint2*)&outp[((size_t)b * 1024 + col) * 1024 + row_base] = pw;
    }
  } else {                          // MODE 7: MLP2 -> d_out f32 + res from xf1_t
    float* outp = (float*)outv;
    #pragma unroll
    for (int c = 0; c < 4; ++c) {
      int col = n0 + c * 16 + ml;
      uint2 rv = *(const uint2*)(resb + ((size_t)b * 1024 + col) * 256 + row_base);
      float r0 = b2f((unsigned short)(rv.x & 0xffff));
      float r1 = b2f((unsigned short)(rv.x >> 16));
      float r2 = b2f((unsigned short)(rv.y & 0xffff));
      float r3 = b2f((unsigned short)(rv.y >> 16));
      outp[((size_t)b * 256 + row_base + 0) * 1024 + col] = acc[c][0] + bias[row_base + 0] + r0;
      outp[((size_t)b * 256 + row_base + 1) * 1024 + col] = acc[c][1] + bias[row_base + 1] + r1;
      outp[((size_t)b * 256 + row_base + 2) * 1024 + col] = acc[c][2] + bias[row_base + 2] + r2;
      outp[((size_t)b * 256 + row_base + 3) * 1024 + col] = acc[c][3] + bias[row_base + 3] + r3;
    }
  }
}

// ---------------------------------------------------------------------------
// Attention v7: 2048 blocks = (b, h, nt of 64 n-rows), 4 waves x 16 rows.
// R8 geometry WITHOUT the register pipeline and WITHOUT tight bounds (the
// two proven spill causes). ~70 regs incl 16 AGPR -> ~7 blocks/CU resident.
// Zero barriers; in-wave LDS C->A transform; max-free deferred softmax.
// ---------------------------------------------------------------------------
__global__ __launch_bounds__(256, 4) void attn_kernel(
    const unsigned short* __restrict__ qt, const unsigned short* __restrict__ kt,
    const unsigned short* __restrict__ vt, unsigned short* __restrict__ ot) {
  int bx = blockIdx.x;
  int nt = bx & 15, h = (bx >> 4) & 15, b = bx >> 8;
  int tid = threadIdx.x, lane = tid & 63, w = tid >> 6;
  int ml = lane & 15, quad = lane >> 4;

  __shared__ unsigned int Pscr[4][2][16][18];  // [wave][buf][n][m-packed u32]
  __shared__ float Ssum[4][16];

  const int n0 = nt * 64 + w * 16;
  const size_t qk_row = ((size_t)b * 16 + h) * 1024;

  short8 qf = {0, 0, 0, 0, 0, 0, 0, 0};
  if (quad < 2) qf = *(const short8*)(qt + (qk_row + n0 + ml) * 16 + quad * 8);

  const floatx4 zf = {0.f, 0.f, 0.f, 0.f};
  floatx4 oacc[4];
  #pragma unroll
  for (int dt = 0; dt < 4; ++dt) oacc[dt] = zf;
  float psum = 0.f;

  const unsigned short* kp = kt + qk_row * 16;
  const unsigned short* vp = vt + ((size_t)b * 1024 + h * 64) * 1024;

  #pragma unroll 2
  for (int mc = 0; mc < 1024; mc += 32) {
    int buf = (mc >> 5) & 1;
    short8 kf[2];
    #pragma unroll
    for (int tt = 0; tt < 2; ++tt) {
      short8 z = {0, 0, 0, 0, 0, 0, 0, 0};
      if (quad < 2)
        z = *(const short8*)(kp + (size_t)(mc + tt * 16 + ml) * 16 + quad * 8);
      kf[tt] = z;
    }
    short8 vf[4];
    #pragma unroll
    for (int dt = 0; dt < 4; ++dt)
      vf[dt] = *(const short8*)(vp + (size_t)(dt * 16 + ml) * 1024 + mc + quad * 8);

    #pragma unroll
    for (int tt = 0; tt < 2; ++tt) {
      floatx4 s = __builtin_amdgcn_mfma_f32_16x16x32_bf16(kf[tt], qf, zf, 0, 0, 0);
      float p0 = __builtin_amdgcn_exp2f(s[0]);
      float p1 = __builtin_amdgcn_exp2f(s[1]);
      float p2 = __builtin_amdgcn_exp2f(s[2]);
      float p3 = __builtin_amdgcn_exp2f(s[3]);
      psum += (p0 + p1) + (p2 + p3);
      uint2 pw; pw.x = f2b2(p0, p1); pw.y = f2b2(p2, p3);
      *(uint2*)&Pscr[w][buf][ml][tt * 8 + quad * 2] = pw;
    }
    {
      uint2 a0 = *(const uint2*)&Pscr[w][buf][ml][quad * 4];
      uint2 a1 = *(const uint2*)&Pscr[w][buf][ml][quad * 4 + 2];
      union { uint4 u; short8 s; } cv;
      cv.u = make_uint4(a0.x, a0.y, a1.x, a1.y);
      short8 af = cv.s;
      #pragma unroll
      for (int dt = 0; dt < 4; ++dt)
        oacc[dt] = __builtin_amdgcn_mfma_f32_16x16x32_bf16(af, vf[dt], oacc[dt], 0, 0, 0);
    }
  }

  float s0 = psum;
  s0 += __shfl_xor(s0, 16, 64);
  s0 += __shfl_xor(s0, 32, 64);
  if (lane < 16) Ssum[w][ml] = s0;
  float4 sv = *(const float4*)&Ssum[w][quad * 4];
  float inv0 = 1.0f / sv.x, inv1 = 1.0f / sv.y;
  float inv2 = 1.0f / sv.z, inv3 = 1.0f / sv.w;
  int nbase = n0 + quad * 4;
  #pragma unroll
  for (int dt = 0; dt < 4; ++dt) {
    int dg = h * 64 + dt * 16 + ml;
    size_t obase = (((size_t)b << 10) + nbase) * 1024 + dg;
    ot[obase + 0 * 1024] = f2b(oacc[dt][0] * inv0);
    ot[obase + 1 * 1024] = f2b(oacc[dt][1] * inv1);
    ot[obase + 2 * 1024] = f2b(oacc[dt][2] * inv2);
    ot[obase + 3 * 1024] = f2b(oacc[dt][3] * inv3);
  }
}

// ---------------------------------------------------------------------------
extern "C" void kernel_launch(void* const* d_in, const int* in_sizes, int n_in,
                              void* d_out, int out_size, void* d_ws, size_t ws_size,
                              hipStream_t stream) {
  const float* x   = (const float*)d_in[0];
  const float* g1  = (const float*)d_in[1];
  const float* b1  = (const float*)d_in[2];
  const float* wq  = (const float*)d_in[3];
  const float* bq  = (const float*)d_in[4];
  const float* wk  = (const float*)d_in[5];
  const float* bk  = (const float*)d_in[6];
  const float* wv  = (const float*)d_in[7];
  const float* bv  = (const float*)d_in[8];
  const float* wp  = (const float*)d_in[9];
  const float* bp  = (const float*)d_in[10];
  const float* g2  = (const float*)d_in[11];
  const float* b2  = (const float*)d_in[12];
  const float* w1  = (const float*)d_in[13];
  const float* bb1 = (const float*)d_in[14];
  const float* w2  = (const float*)d_in[15];
  const float* bb2 = (const float*)d_in[16];

  char* ws = (char*)d_ws;
  float* bnacc   = (float*)ws;                  // 1024 f: sum1,sq1 | sum2,sq2
  float* biasqkv = (float*)(ws + 4096);         // 1536 f
  unsigned short* y_t  = (unsigned short*)(ws + 16384);    // bf16 [8][1024][256]
  unsigned short* qt   = y_t + (size_t)2 * 1024 * 1024;    // bf16 [8][16][1024][16]
  unsigned short* kt   = qt  + (size_t)2 * 1024 * 1024;    // = qt + 2097152
  unsigned short* vt   = kt  + (size_t)2 * 1024 * 1024;    // = qt + 4194304
  unsigned short* ot   = vt  + (size_t)8 * 1024 * 1024;    // bf16 [8][1024][1024] n-major
  unsigned short* xf1t = ot  + (size_t)8 * 1024 * 1024;    // bf16 [8][1024][256] n-major
  unsigned short* wb   = xf1t + (size_t)2 * 1024 * 1024;
  unsigned short* hb_t = ot;          // reuse: ot dead after proj
  float* outp = (float*)d_out;

  unsigned short* wqkvb = wb;         // rows 0..255 wq | 256..511 wk | 512..1535 wv
  unsigned short* wpb = wb + 393216;
  unsigned short* w1b = wb + 655360;
  unsigned short* w2b = wb + 917504;
  const unsigned short* nub = nullptr;
  const float* nuf = nullptr;

  hipMemsetAsync(bnacc, 0, 4096, stream);
  prep<<<dim3(3206), dim3(256), 0, stream>>>(
      wq, wk, wv, wp, w1, w2, wb, x, bnacc, bq, bk, bv, biasqkv);

  // --- attention branch ---
  bn_apply_t<<<dim3(16, 4, 8), dim3(256), 0, stream>>>(x, bnacc, g1, b1, y_t);
  gemm3<4><<<dim3(16, 24, 8), dim3(256), 0, stream>>>(
      wqkvb, y_t, biasqkv, nuf, nub, qt, nullptr, nuf, nuf, nuf, 1536, 256);
  attn_kernel<<<dim3(2048), dim3(256), 0, stream>>>(qt, kt, vt, ot);
  gemm3<5><<<dim3(16, 4, 8), dim3(256), 0, stream>>>(
      wpb, ot, bp, x, nub, xf1t, bnacc + 512, nuf, nuf, nuf, 256, 1024);

  // --- MLP branch ---
  gemm3<6><<<dim3(16, 16, 8), dim3(256), 0, stream>>>(
      w1b, xf1t, bb1, nuf, nub, hb_t, nullptr, bnacc + 512, g2, b2, 1024, 256);
  gemm3<7><<<dim3(16, 4, 8), dim3(256), 0, stream>>>(
      w2b, hb_t, bb2, nuf, xf1t, outp, nullptr, nuf, nuf, nuf, 256, 1024);
}

// Round 12
// 240.012 us; speedup vs baseline: 1.3229x; 1.3229x over previous
//
#include <hip/hip_runtime.h>
#include <hip/hip_bf16.h>
#include <cstdint>

// ---------------------------------------------------------------------------
// TextBlock: BN -> {q,k,v} -> MHSA (NH=16, KD=16, D=64, N=1024) -> proj -> +res
//            -> BN -> MLP(1024, relu6) -> +res.   B=8, C=256.
// I/O FLOAT32. Intermediates bf16 for MFMA, fp32 accumulation.
// R12: best-of composition. Attn = EXACT R6 kernel (76us proven x3):
//      1024 blocks x 128 rows, 2 rowgroups/wave (work-per-wave is the binding
//      constraint, NOT occupancy; 16-row waves regressed 2x in R11).
//      Chain = R11 (non-attn ~163us): proj writes n-major bf16 xf1_t with
//      fused BN2 stats; MLP1 inline-BN at staging; MLP2 res from xf1_t.
// ---------------------------------------------------------------------------

typedef __attribute__((ext_vector_type(8))) short short8;
typedef __attribute__((ext_vector_type(4))) float floatx4;

#define QK_SC 5.770780163555851f   // sqrt(kd)=4 times log2(e), folded into Q

__device__ __forceinline__ float b2f(unsigned short u) {
  union { unsigned int i; float f; } x; x.i = ((unsigned int)u) << 16; return x.f;
}
__device__ __forceinline__ unsigned short f2b(float f) {
  union { float f; unsigned int i; } x; x.f = f;
  unsigned int r = x.i + 0x7FFFu + ((x.i >> 16) & 1u);   // RNE
  return (unsigned short)(r >> 16);
}
// packed f32x2 -> bf16x2 (v_cvt_pk_bf16_f32 on gfx950)
__device__ __forceinline__ unsigned int f2b2(float a, float b) {
  __hip_bfloat162 h = __float22bfloat162_rn(make_float2(a, b));
  union { __hip_bfloat162 v; unsigned int u; } x; x.v = h; return x.u;
}

// ---------------------------------------------------------------------------
// prep: blocks 0..1151 convert the 6 weight mats f32->bf16 into wb;
//       blocks 1152..3199 accumulate BN1 partial sums of x into bnacc;
//       blocks 3200..3205 concat bq|bk|bv into biasqkv.
// ---------------------------------------------------------------------------
__global__ __launch_bounds__(256) void prep(
    const float* __restrict__ s0, const float* __restrict__ s1,
    const float* __restrict__ s2, const float* __restrict__ s3,
    const float* __restrict__ s4, const float* __restrict__ s5,
    unsigned short* __restrict__ dst,
    const float* __restrict__ x, float* __restrict__ acc,
    const float* __restrict__ bq, const float* __restrict__ bk,
    const float* __restrict__ bv, float* __restrict__ biasqkv) {
  int blk = blockIdx.x, t = threadIdx.x;
  if (blk < 1152) {
    int i = blk * 256 + t;   // float4-group index
    if (i >= 294912) return;
    const float* s; int li; size_t dbase;
    if (i < 16384)       { s = s0; li = i;          dbase = 0; }
    else if (i < 32768)  { s = s1; li = i - 16384;  dbase = 65536; }
    else if (i < 98304)  { s = s2; li = i - 32768;  dbase = 131072; }
    else if (i < 163840) { s = s3; li = i - 98304;  dbase = 393216; }
    else if (i < 229376) { s = s4; li = i - 163840; dbase = 655360; }
    else                 { s = s5; li = i - 229376; dbase = 917504; }
    float4 v = ((const float4*)s)[li];
    uint2 o; o.x = f2b2(v.x, v.y); o.y = f2b2(v.z, v.w);
    ((uint2*)(dst + dbase))[li] = o;
  } else if (blk < 3200) {
    int blk2 = blk - 1152;
    int b = blk2 >> 8, c = blk2 & 255;
    const float* p = x + (((size_t)(b * 256 + c)) << 10);
    float4 v = ((const float4*)p)[t];
    float s = (v.x + v.y) + (v.z + v.w);
    float s2 = (v.x * v.x + v.y * v.y) + (v.z * v.z + v.w * v.w);
    #pragma unroll
    for (int o = 32; o > 0; o >>= 1) { s += __shfl_down(s, o, 64); s2 += __shfl_down(s2, o, 64); }
    __shared__ float rs[4], rs2[4];
    int w = t >> 6;
    if ((t & 63) == 0) { rs[w] = s; rs2[w] = s2; }
    __syncthreads();
    if (t == 0) {
      atomicAdd(acc + c, (rs[0] + rs[1]) + (rs[2] + rs[3]));
      atomicAdd(acc + 256 + c, (rs2[0] + rs2[1]) + (rs2[2] + rs2[3]));
    }
  } else {
    int i = (blk - 3200) * 256 + t;   // 0..1535
    float v = (i < 256) ? bq[i] : (i < 512) ? bk[i - 256] : bv[i - 512];
    biasqkv[i] = v;
  }
}

// ---------------------------------------------------------------------------
// BN apply + transpose (finalize fused): x[b][c][n] f32 -> y_t[b][n][c] bf16.
// ---------------------------------------------------------------------------
__global__ __launch_bounds__(256) void bn_apply_t(
    const float* __restrict__ x, const float* __restrict__ acc,
    const float* __restrict__ g, const float* __restrict__ bb,
    unsigned short* __restrict__ yt) {
  int nt = blockIdx.x, ct = blockIdx.y, b = blockIdx.z;
  int t = threadIdx.x;
  __shared__ unsigned short T[64][72];
  {
    int r = t >> 2, g4 = (t & 3) * 16;
    int c = ct * 64 + r;
    float m = acc[c] * (1.0f / 8192.0f);
    float var = acc[256 + c] * (1.0f / 8192.0f) - m * m;
    float scl = g[c] * rsqrtf(var + 1e-5f);
    float shf = bb[c] - m * scl;
    const float* p = x + (((size_t)(b * 256 + c)) << 10) + nt * 64 + g4;
    float4 u0 = *(const float4*)(p);
    float4 u1 = *(const float4*)(p + 4);
    float4 u2 = *(const float4*)(p + 8);
    float4 u3 = *(const float4*)(p + 12);
    uint4 o0, o1;
    o0.x = f2b2(fmaf(u0.x, scl, shf), fmaf(u0.y, scl, shf));
    o0.y = f2b2(fmaf(u0.z, scl, shf), fmaf(u0.w, scl, shf));
    o0.z = f2b2(fmaf(u1.x, scl, shf), fmaf(u1.y, scl, shf));
    o0.w = f2b2(fmaf(u1.z, scl, shf), fmaf(u1.w, scl, shf));
    o1.x = f2b2(fmaf(u2.x, scl, shf), fmaf(u2.y, scl, shf));
    o1.y = f2b2(fmaf(u2.z, scl, shf), fmaf(u2.w, scl, shf));
    o1.z = f2b2(fmaf(u3.x, scl, shf), fmaf(u3.y, scl, shf));
    o1.w = f2b2(fmaf(u3.z, scl, shf), fmaf(u3.w, scl, shf));
    *(uint4*)&T[r][g4] = o0;
    *(uint4*)&T[r][g4 + 8] = o1;
  }
  __syncthreads();
  {
    int nr = t >> 2, cg = (t & 3) * 16;
    unsigned int ob[8];
    #pragma unroll
    for (int j = 0; j < 8; ++j) {
      unsigned int lo = T[cg + 2 * j][nr];
      unsigned int hi = T[cg + 2 * j + 1][nr];
      ob[j] = lo | (hi << 16);
    }
    unsigned short* orow = yt + ((size_t)(b * 1024 + nt * 64 + nr)) * 256 + ct * 64 + cg;
    *(uint4*)&orow[0] = make_uint4(ob[0], ob[1], ob[2], ob[3]);
    *(uint4*)&orow[8] = make_uint4(ob[4], ob[5], ob[6], ob[7]);
  }
}

// ---------------------------------------------------------------------------
// MFMA GEMM (64x64, BK=64, (256,4) - proven R7 shape):
//   out = W[M,K] @ Bn_b[N=1024,K]^T + bias (...)
// MODE 4: fused QKV (M=1536): rows<256 q*SC | <512 k (per-head [b][h][n][16])
//         | else v k-major bf16. kt at out+2097152, vt at out+4194304.
// MODE 5: proj: out xf1_t N-MAJOR bf16 [b][1024][256] + x residual (f32
//         c-major) + fused BN2 stats atomics into stats[].
// MODE 6: MLP1: B-staging applies BN2 inline (scl/shf from bnin/g/bb, LDS
//         precomputed) + relu6 -> N-MAJOR bf16 out [b][1024][1024] (hb_t).
// MODE 7: MLP2: res gathered from resb (bf16 n-major xf1_t) -> f32 out
//         c-major [b][256][1024] (d_out).
// ---------------------------------------------------------------------------
template <int MODE>
__global__ __launch_bounds__(256, 4) void gemm3(
    const unsigned short* __restrict__ W, const unsigned short* __restrict__ Bn,
    const float* __restrict__ bias, const float* __restrict__ resf,
    const unsigned short* __restrict__ resb, void* __restrict__ outv,
    float* __restrict__ stats, const float* __restrict__ bnin,
    const float* __restrict__ g, const float* __restrict__ bb, int M, int K) {
  int n0 = blockIdx.x * 64, m0 = blockIdx.y * 64, b = blockIdx.z;
  int t = threadIdx.x, lane = t & 63, w = t >> 6;
  int ml = lane & 15, quad = lane >> 4;

  __shared__ unsigned short Wt[64][72];
  __shared__ unsigned short Yt[64][72];
  __shared__ float Scl[256], Shf[256];

  if (MODE == 6) {   // precompute BN2 scale/shift (c = t)
    float m = bnin[t] * (1.0f / 8192.0f);
    float var = bnin[256 + t] * (1.0f / 8192.0f) - m * m;
    float scl = g[t] * rsqrtf(var + 1e-5f);
    Scl[t] = scl;
    Shf[t] = bb[t] - m * scl;
    __syncthreads();
  }

  const unsigned short* Bp = Bn + (size_t)b * 1024 * K;
  int sr = t >> 2, scg = (t & 3) * 16;
  const unsigned short* wrow = W + (size_t)(m0 + sr) * K + scg;
  const unsigned short* brow = Bp + (size_t)(n0 + sr) * K + scg;

  floatx4 acc[4];
  #pragma unroll
  for (int i = 0; i < 4; ++i) acc[i] = (floatx4){0.f, 0.f, 0.f, 0.f};

  for (int k0 = 0; k0 < K; k0 += 64) {
    *(uint4*)&Wt[sr][scg]     = *(const uint4*)(wrow + k0);
    *(uint4*)&Wt[sr][scg + 8] = *(const uint4*)(wrow + k0 + 8);
    if (MODE == 6) {   // BN2-apply inline: y2 = xf1*scl + shf
      uint4 r0 = *(const uint4*)(brow + k0);
      uint4 r1 = *(const uint4*)(brow + k0 + 8);
      int cb = k0 + scg;
      float4 s0 = *(const float4*)&Scl[cb],     h0 = *(const float4*)&Shf[cb];
      float4 s1 = *(const float4*)&Scl[cb + 4], h1 = *(const float4*)&Shf[cb + 4];
      float4 s2 = *(const float4*)&Scl[cb + 8], h2 = *(const float4*)&Shf[cb + 8];
      float4 s3 = *(const float4*)&Scl[cb + 12], h3 = *(const float4*)&Shf[cb + 12];
      uint4 o0, o1;
      o0.x = f2b2(fmaf(b2f(r0.x & 0xffff), s0.x, h0.x), fmaf(b2f(r0.x >> 16), s0.y, h0.y));
      o0.y = f2b2(fmaf(b2f(r0.y & 0xffff), s0.z, h0.z), fmaf(b2f(r0.y >> 16), s0.w, h0.w));
      o0.z = f2b2(fmaf(b2f(r0.z & 0xffff), s1.x, h1.x), fmaf(b2f(r0.z >> 16), s1.y, h1.y));
      o0.w = f2b2(fmaf(b2f(r0.w & 0xffff), s1.z, h1.z), fmaf(b2f(r0.w >> 16), s1.w, h1.w));
      o1.x = f2b2(fmaf(b2f(r1.x & 0xffff), s2.x, h2.x), fmaf(b2f(r1.x >> 16), s2.y, h2.y));
      o1.y = f2b2(fmaf(b2f(r1.y & 0xffff), s2.z, h2.z), fmaf(b2f(r1.y >> 16), s2.w, h2.w));
      o1.z = f2b2(fmaf(b2f(r1.z & 0xffff), s3.x, h3.x), fmaf(b2f(r1.z >> 16), s3.y, h3.y));
      o1.w = f2b2(fmaf(b2f(r1.w & 0xffff), s3.z, h3.z), fmaf(b2f(r1.w >> 16), s3.w, h3.w));
      *(uint4*)&Yt[sr][scg]     = o0;
      *(uint4*)&Yt[sr][scg + 8] = o1;
    } else {
      *(uint4*)&Yt[sr][scg]     = *(const uint4*)(brow + k0);
      *(uint4*)&Yt[sr][scg + 8] = *(const uint4*)(brow + k0 + 8);
    }
    __syncthreads();
    short8 a0 = *(const short8*)&Wt[w * 16 + ml][quad * 8];
    short8 a1 = *(const short8*)&Wt[w * 16 + ml][32 + quad * 8];
    #pragma unroll
    for (int nt2 = 0; nt2 < 4; ++nt2) {
      short8 b0 = *(const short8*)&Yt[nt2 * 16 + ml][quad * 8];
      short8 b1 = *(const short8*)&Yt[nt2 * 16 + ml][32 + quad * 8];
      acc[nt2] = __builtin_amdgcn_mfma_f32_16x16x32_bf16(a0, b0, acc[nt2], 0, 0, 0);
      acc[nt2] = __builtin_amdgcn_mfma_f32_16x16x32_bf16(a1, b1, acc[nt2], 0, 0, 0);
    }
    __syncthreads();
  }

  int row_base = m0 + w * 16 + quad * 4;

  if (MODE == 4) {
    int hh = row_base >> 4;       // 0..95
    float b0 = bias[row_base + 0], b1 = bias[row_base + 1];
    float b2 = bias[row_base + 2], b3 = bias[row_base + 3];
    if (hh < 32) {                // q (hh<16) or k
      unsigned short* qkout = (unsigned short*)outv + ((hh < 16) ? 0 : 2097152);
      float os = (hh < 16) ? QK_SC : 1.0f;
      int head = hh & 15, kd0 = row_base & 15;
      #pragma unroll
      for (int c = 0; c < 4; ++c) {
        int col = n0 + c * 16 + ml;
        uint2 pw;
        pw.x = f2b2((acc[c][0] + b0) * os, (acc[c][1] + b1) * os);
        pw.y = f2b2((acc[c][2] + b2) * os, (acc[c][3] + b3) * os);
        *(uint2*)&qkout[(((size_t)b * 16 + head) * 1024 + col) * 16 + kd0] = pw;
      }
    } else {                      // v: k-major [b][d][1024]
      unsigned short* vout = (unsigned short*)outv + 4194304;
      int d0 = row_base - 512;
      #pragma unroll
      for (int c = 0; c < 4; ++c) {
        int col = n0 + c * 16 + ml;
        vout[((size_t)b * 1024 + d0 + 0) * 1024 + col] = f2b(acc[c][0] + b0);
        vout[((size_t)b * 1024 + d0 + 1) * 1024 + col] = f2b(acc[c][1] + b1);
        vout[((size_t)b * 1024 + d0 + 2) * 1024 + col] = f2b(acc[c][2] + b2);
        vout[((size_t)b * 1024 + d0 + 3) * 1024 + col] = f2b(acc[c][3] + b3);
      }
    }
  } else if (MODE == 5) {          // proj -> xf1_t n-major bf16 + stats
    unsigned short* outp = (unsigned short*)outv;
    float vsum[4] = {0.f, 0.f, 0.f, 0.f}, vsq[4] = {0.f, 0.f, 0.f, 0.f};
    #pragma unroll
    for (int c = 0; c < 4; ++c) {
      int col = n0 + c * 16 + ml;
      float v0 = acc[c][0] + bias[row_base + 0] + resf[((size_t)b * 256 + row_base + 0) * 1024 + col];
      float v1 = acc[c][1] + bias[row_base + 1] + resf[((size_t)b * 256 + row_base + 1) * 1024 + col];
      float v2 = acc[c][2] + bias[row_base + 2] + resf[((size_t)b * 256 + row_base + 2) * 1024 + col];
      float v3 = acc[c][3] + bias[row_base + 3] + resf[((size_t)b * 256 + row_base + 3) * 1024 + col];
      vsum[0] += v0; vsq[0] += v0 * v0;
      vsum[1] += v1; vsq[1] += v1 * v1;
      vsum[2] += v2; vsq[2] += v2 * v2;
      vsum[3] += v3; vsq[3] += v3 * v3;
      uint2 pw; pw.x = f2b2(v0, v1); pw.y = f2b2(v2, v3);
      *(uint2*)&outp[((size_t)b * 1024 + col) * 256 + row_base] = pw;
    }
    #pragma unroll
    for (int r = 0; r < 4; ++r) {
      float s = vsum[r], q = vsq[r];
      #pragma unroll
      for (int o = 1; o < 16; o <<= 1) { s += __shfl_xor(s, o, 64); q += __shfl_xor(q, o, 64); }
      if (ml == 0) {
        atomicAdd(stats + row_base + r, s);
        atomicAdd(stats + 256 + row_base + r, q);
      }
    }
  } else if (MODE == 6) {          // MLP1 -> hb_t n-major bf16 + relu6
    unsigned short* outp = (unsigned short*)outv;
    #pragma unroll
    for (int c = 0; c < 4; ++c) {
      int col = n0 + c * 16 + ml;
      float v0 = fminf(fmaxf(acc[c][0] + bias[row_base + 0], 0.f), 6.f);
      float v1 = fminf(fmaxf(acc[c][1] + bias[row_base + 1], 0.f), 6.f);
      float v2 = fminf(fmaxf(acc[c][2] + bias[row_base + 2], 0.f), 6.f);
      float v3 = fminf(fmaxf(acc[c][3] + bias[row_base + 3], 0.f), 6.f);
      uint2 pw; pw.x = f2b2(v0, v1); pw.y = f2b2(v2, v3);
      *(uint2*)&outp[((size_t)b * 1024 + col) * 1024 + row_base] = pw;
    }
  } else {                          // MODE 7: MLP2 -> d_out f32 + res from xf1_t
    float* outp = (float*)outv;
    #pragma unroll
    for (int c = 0; c < 4; ++c) {
      int col = n0 + c * 16 + ml;
      uint2 rv = *(const uint2*)(resb + ((size_t)b * 1024 + col) * 256 + row_base);
      float r0 = b2f((unsigned short)(rv.x & 0xffff));
      float r1 = b2f((unsigned short)(rv.x >> 16));
      float r2 = b2f((unsigned short)(rv.y & 0xffff));
      float r3 = b2f((unsigned short)(rv.y >> 16));
      outp[((size_t)b * 256 + row_base + 0) * 1024 + col] = acc[c][0] + bias[row_base + 0] + r0;
      outp[((size_t)b * 256 + row_base + 1) * 1024 + col] = acc[c][1] + bias[row_base + 1] + r1;
      outp[((size_t)b * 256 + row_base + 2) * 1024 + col] = acc[c][2] + bias[row_base + 2] + r2;
      outp[((size_t)b * 256 + row_base + 3) * 1024 + col] = acc[c][3] + bias[row_base + 3] + r3;
    }
  }
}

// ---------------------------------------------------------------------------
// Attention (EXACT R6 kernel, (256,4), proven 76us x3): 1024 blocks =
// (b, h, nt of 128 n-rows), 4 waves x 32 rows (2 rowgroups share each K/V
// fetch - work-per-wave is the binding constraint). Zero barriers.
// NOTE: bounds 5/6 spill (unified VGPR+AGPR ~95-100); 16-row waves halve
// arithmetic per load and regress 2x. Do not touch.
// ---------------------------------------------------------------------------
__global__ __launch_bounds__(256, 4) void attn_kernel(
    const unsigned short* __restrict__ qt, const unsigned short* __restrict__ kt,
    const unsigned short* __restrict__ vt, unsigned short* __restrict__ ot) {
  int bx = blockIdx.x;
  int nt = bx & 7, h = (bx >> 3) & 15, b = bx >> 7;
  int tid = threadIdx.x, lane = tid & 63, w = tid >> 6;
  int ml = lane & 15, quad = lane >> 4;

  __shared__ unsigned int Pscr[4][2][2][16][18];  // [wave][buf][rg][n][m-packed u32]
  __shared__ float Ssum[4][2][16];

  const int n0 = nt * 128 + w * 32;
  const size_t qk_row = ((size_t)b * 16 + h) * 1024;

  short8 qf[2];
  #pragma unroll
  for (int rg = 0; rg < 2; ++rg) {
    short8 z = {0, 0, 0, 0, 0, 0, 0, 0};
    if (quad < 2)
      z = *(const short8*)(qt + (qk_row + n0 + rg * 16 + ml) * 16 + quad * 8);
    qf[rg] = z;
  }

  const floatx4 zf = {0.f, 0.f, 0.f, 0.f};
  floatx4 oacc[2][4];
  #pragma unroll
  for (int rg = 0; rg < 2; ++rg)
    #pragma unroll
    for (int dt = 0; dt < 4; ++dt) oacc[rg][dt] = zf;
  float psum0 = 0.f, psum1 = 0.f;

  const unsigned short* kp = kt + qk_row * 16;
  const unsigned short* vp = vt + ((size_t)b * 1024 + h * 64) * 1024;

  #pragma unroll 2
  for (int mc = 0; mc < 1024; mc += 32) {
    int buf = (mc >> 5) & 1;
    short8 kf[2];
    #pragma unroll
    for (int tt = 0; tt < 2; ++tt) {
      short8 z = {0, 0, 0, 0, 0, 0, 0, 0};
      if (quad < 2)
        z = *(const short8*)(kp + (size_t)(mc + tt * 16 + ml) * 16 + quad * 8);
      kf[tt] = z;
    }
    short8 vf[4];
    #pragma unroll
    for (int dt = 0; dt < 4; ++dt)
      vf[dt] = *(const short8*)(vp + (size_t)(dt * 16 + ml) * 1024 + mc + quad * 8);

    #pragma unroll
    for (int rg = 0; rg < 2; ++rg) {
      #pragma unroll
      for (int tt = 0; tt < 2; ++tt) {
        floatx4 s = __builtin_amdgcn_mfma_f32_16x16x32_bf16(kf[tt], qf[rg], zf, 0, 0, 0);
        float p0 = __builtin_amdgcn_exp2f(s[0]);
        float p1 = __builtin_amdgcn_exp2f(s[1]);
        float p2 = __builtin_amdgcn_exp2f(s[2]);
        float p3 = __builtin_amdgcn_exp2f(s[3]);
        if (rg == 0) psum0 += (p0 + p1) + (p2 + p3);
        else         psum1 += (p0 + p1) + (p2 + p3);
        uint2 pw; pw.x = f2b2(p0, p1); pw.y = f2b2(p2, p3);
        *(uint2*)&Pscr[w][buf][rg][ml][tt * 8 + quad * 2] = pw;
      }
    }
    #pragma unroll
    for (int rg = 0; rg < 2; ++rg) {
      uint2 a0 = *(const uint2*)&Pscr[w][buf][rg][ml][quad * 4];
      uint2 a1 = *(const uint2*)&Pscr[w][buf][rg][ml][quad * 4 + 2];
      union { uint4 u; short8 s; } cv;
      cv.u = make_uint4(a0.x, a0.y, a1.x, a1.y);
      short8 af = cv.s;
      #pragma unroll
      for (int dt = 0; dt < 4; ++dt)
        oacc[rg][dt] = __builtin_amdgcn_mfma_f32_16x16x32_bf16(af, vf[dt], oacc[rg][dt], 0, 0, 0);
    }
  }

  {
    float s0 = psum0;
    s0 += __shfl_xor(s0, 16, 64);
    s0 += __shfl_xor(s0, 32, 64);
    float s1 = psum1;
    s1 += __shfl_xor(s1, 16, 64);
    s1 += __shfl_xor(s1, 32, 64);
    if (lane < 16) { Ssum[w][0][ml] = s0; Ssum[w][1][ml] = s1; }
  }
  #pragma unroll
  for (int rg = 0; rg < 2; ++rg) {
    float4 sv = *(const float4*)&Ssum[w][rg][quad * 4];
    float inv0 = 1.0f / sv.x, inv1 = 1.0f / sv.y;
    float inv2 = 1.0f / sv.z, inv3 = 1.0f / sv.w;
    int nbase = n0 + rg * 16 + quad * 4;
    #pragma unroll
    for (int dt = 0; dt < 4; ++dt) {
      int dg = h * 64 + dt * 16 + ml;
      size_t obase = (((size_t)b << 10) + nbase) * 1024 + dg;
      ot[obase + 0 * 1024] = f2b(oacc[rg][dt][0] * inv0);
      ot[obase + 1 * 1024] = f2b(oacc[rg][dt][1] * inv1);
      ot[obase + 2 * 1024] = f2b(oacc[rg][dt][2] * inv2);
      ot[obase + 3 * 1024] = f2b(oacc[rg][dt][3] * inv3);
    }
  }
}

// ---------------------------------------------------------------------------
extern "C" void kernel_launch(void* const* d_in, const int* in_sizes, int n_in,
                              void* d_out, int out_size, void* d_ws, size_t ws_size,
                              hipStream_t stream) {
  const float* x   = (const float*)d_in[0];
  const float* g1  = (const float*)d_in[1];
  const float* b1  = (const float*)d_in[2];
  const float* wq  = (const float*)d_in[3];
  const float* bq  = (const float*)d_in[4];
  const float* wk  = (const float*)d_in[5];
  const float* bk  = (const float*)d_in[6];
  const float* wv  = (const float*)d_in[7];
  const float* bv  = (const float*)d_in[8];
  const float* wp  = (const float*)d_in[9];
  const float* bp  = (const float*)d_in[10];
  const float* g2  = (const float*)d_in[11];
  const float* b2  = (const float*)d_in[12];
  const float* w1  = (const float*)d_in[13];
  const float* bb1 = (const float*)d_in[14];
  const float* w2  = (const float*)d_in[15];
  const float* bb2 = (const float*)d_in[16];

  char* ws = (char*)d_ws;
  float* bnacc   = (float*)ws;                  // 1024 f: sum1,sq1 | sum2,sq2
  float* biasqkv = (float*)(ws + 4096);         // 1536 f
  unsigned short* y_t  = (unsigned short*)(ws + 16384);    // bf16 [8][1024][256]
  unsigned short* qt   = y_t + (size_t)2 * 1024 * 1024;    // bf16 [8][16][1024][16]
  unsigned short* kt   = qt  + (size_t)2 * 1024 * 1024;    // = qt + 2097152
  unsigned short* vt   = kt  + (size_t)2 * 1024 * 1024;    // = qt + 4194304
  unsigned short* ot   = vt  + (size_t)8 * 1024 * 1024;    // bf16 [8][1024][1024] n-major
  unsigned short* xf1t = ot  + (size_t)8 * 1024 * 1024;    // bf16 [8][1024][256] n-major
  unsigned short* wb   = xf1t + (size_t)2 * 1024 * 1024;
  unsigned short* hb_t = ot;          // reuse: ot dead after proj
  float* outp = (float*)d_out;

  unsigned short* wqkvb = wb;         // rows 0..255 wq | 256..511 wk | 512..1535 wv
  unsigned short* wpb = wb + 393216;
  unsigned short* w1b = wb + 655360;
  unsigned short* w2b = wb + 917504;
  const unsigned short* nub = nullptr;
  const float* nuf = nullptr;

  hipMemsetAsync(bnacc, 0, 4096, stream);
  prep<<<dim3(3206), dim3(256), 0, stream>>>(
      wq, wk, wv, wp, w1, w2, wb, x, bnacc, bq, bk, bv, biasqkv);

  // --- attention branch ---
  bn_apply_t<<<dim3(16, 4, 8), dim3(256), 0, stream>>>(x, bnacc, g1, b1, y_t);
  gemm3<4><<<dim3(16, 24, 8), dim3(256), 0, stream>>>(
      wqkvb, y_t, biasqkv, nuf, nub, qt, nullptr, nuf, nuf, nuf, 1536, 256);
  attn_kernel<<<dim3(1024), dim3(256), 0, stream>>>(qt, kt, vt, ot);
  gemm3<5><<<dim3(16, 4, 8), dim3(256), 0, stream>>>(
      wpb, ot, bp, x, nub, xf1t, bnacc + 512, nuf, nuf, nuf, 256, 1024);

  // --- MLP branch ---
  gemm3<6><<<dim3(16, 16, 8), dim3(256), 0, stream>>>(
      w1b, xf1t, bb1, nuf, nub, hb_t, nullptr, bnacc + 512, g2, b2, 1024, 256);
  gemm3<7><<<dim3(16, 4, 8), dim3(256), 0, stream>>>(
      w2b, hb_t, bb2, nuf, xf1t, outp, nullptr, nuf, nuf, nuf, 256, 1024);
}